// Round 15
// baseline (75.661 us; speedup 1.0000x reference)
//
#include <hip/hip_runtime.h>
#include <hip/hip_bf16.h>

#define N      8192
#define D_IN   30
#define HID    32
#define D_OUT  30
#define FFD    128
#define ZC     34
#define JGC    16     // j-split groups
#define NCH    4      // chunks (128 rows) per jg = N/(JGC*128)
#define NCHUNK 64     // total 128-row chunks
#define DCUT2  48.0f  // scaled AABB dist^2 cut  (= 2*D, D=24 -> decay 2^-24)

typedef __attribute__((ext_vector_type(8))) short short8;
typedef __attribute__((ext_vector_type(16))) float f32x16;

static __device__ __forceinline__ ushort f2bf(float x) {
    uint32_t u = __float_as_uint(x);
    uint32_t r = (u + 0x7fffu + ((u >> 16) & 1u)) >> 16;   // RTNE
    return (ushort)r;
}
static __device__ __forceinline__ float bf2f(ushort u) {
    return __uint_as_float(((uint32_t)u) << 16);
}
static __device__ __forceinline__ float rdlane(float v, int l) {
    return __uint_as_float(__builtin_amdgcn_readlane(__float_as_uint(v), l));
}

// ---------------------------------------------------------------------------
// Sort pipeline: 12-bit Morton key (4 bits/axis over [-3,3]) -> counting sort.
// ---------------------------------------------------------------------------
__global__ __launch_bounds__(256) void dv_hist_kernel(
    const float* __restrict__ Z, int* __restrict__ key, int* __restrict__ hist)
{
    const int i = blockIdx.x * 256 + threadIdx.x;
    const float* z = Z + (size_t)i * ZC;
    float x = z[D_IN], y = z[D_IN + 1], w = z[D_IN + 2];
    int qx = (int)((x + 3.f) * (16.f / 6.f)); qx = qx < 0 ? 0 : (qx > 15 ? 15 : qx);
    int qy = (int)((y + 3.f) * (16.f / 6.f)); qy = qy < 0 ? 0 : (qy > 15 ? 15 : qy);
    int qz = (int)((w + 3.f) * (16.f / 6.f)); qz = qz < 0 ? 0 : (qz > 15 ? 15 : qz);
    int k = 0;
#pragma unroll
    for (int b = 0; b < 4; ++b) {
        k |= ((qx >> b) & 1) << (3 * b + 2);
        k |= ((qy >> b) & 1) << (3 * b + 1);
        k |= ((qz >> b) & 1) << (3 * b);
    }
    key[i] = k;
    atomicAdd(&hist[k], 1);
}

__global__ __launch_bounds__(256) void dv_scan_kernel(
    const int* __restrict__ hist, int* __restrict__ offs)
{
    __shared__ int ls[256];
    const int t = threadIdx.x;
    int loc[16], s = 0;
#pragma unroll
    for (int k = 0; k < 16; ++k) { loc[k] = hist[t * 16 + k]; s += loc[k]; }
    ls[t] = s;
    __syncthreads();
    for (int d = 1; d < 256; d <<= 1) {
        int v = (t >= d) ? ls[t - d] : 0;
        __syncthreads();
        ls[t] += v;
        __syncthreads();
    }
    int excl = ls[t] - s;
#pragma unroll
    for (int k = 0; k < 16; ++k) { offs[t * 16 + k] = excl; excl += loc[k]; }
}

__global__ __launch_bounds__(256) void dv_scatter_kernel(
    const int* __restrict__ key, int* __restrict__ offs, int* __restrict__ perm)
{
    const int i = blockIdx.x * 256 + threadIdx.x;
    int dst = atomicAdd(&offs[key[i]], 1);
    perm[dst] = i;
}

// ---------------------------------------------------------------------------
// Kernel A: sorted-domain QKV -> bf16; VWo^T (row31=1 -> rowsum); negated
// split-bf16 gate tables (gate MFMA = +D); scaled positions for AABB;
// W2e = W2@We, b2e = b2@We + be.
// ---------------------------------------------------------------------------
__global__ __launch_bounds__(256) void dv_qkv_kernel(
    const float* __restrict__ Z, const int* __restrict__ perm,
    const float* __restrict__ Wq, const float* __restrict__ bq,
    const float* __restrict__ Wk, const float* __restrict__ bk,
    const float* __restrict__ Wv, const float* __restrict__ bv,
    const float* __restrict__ Wo,
    const float* __restrict__ W2, const float* __restrict__ We,
    const float* __restrict__ b2, const float* __restrict__ be,
    ushort* __restrict__ Qb, ushort* __restrict__ Kb,
    ushort* __restrict__ VWot, ushort* __restrict__ KA,
    ushort* __restrict__ QB, float4* __restrict__ pos_s,
    float* __restrict__ W2e, float* __restrict__ b2e)
{
    __shared__ ushort sv[8][33];
    const int t = blockIdx.x * 256 + threadIdx.x;
    const int i = t >> 5;
    const int h = t & 31;
    const int orig = perm[i];
    const float* z = Z + (size_t)orig * ZC;

    float q = bq[h], k = bk[h], v = bv[h];
#pragma unroll
    for (int d = 0; d < D_IN; ++d) {
        float zf = z[d];
        q = fmaf(zf, Wq[d * HID + h], q);
        k = fmaf(zf, Wk[d * HID + h], k);
        v = fmaf(zf, Wv[d * HID + h], v);
    }
    const float QS = 0.17677669529663687f * 1.4426950408889634f; // log2e/sqrt(32)
    Qb[(size_t)i * HID + h] = f2bf(q * QS);
    Kb[(size_t)i * HID + h] = f2bf(k);
    sv[threadIdx.x >> 5][h] = f2bf(v);

    if (h == 0) {
        float p0 = z[D_IN], p1 = z[D_IN + 1], p2 = z[D_IN + 2];
        const float C2 = 1.4426950408889634f / 0.18f;   // log2e/(2*sigma^2)
        const float SC = sqrtf(2.0f * C2);
        float px = p0 * SC, py = p1 * SC, pz = p2 * SC;
        float w  = -C2 * (p0 * p0 + p1 * p1 + p2 * p2);
        pos_s[i] = make_float4(px, py, pz, 0.f);
        ushort phx = f2bf(px), phy = f2bf(py), phz = f2bf(pz);
        ushort plx = f2bf(px - bf2f(phx));
        ushort ply = f2bf(py - bf2f(phy));
        ushort plz = f2bf(pz - bf2f(phz));
        ushort wh  = f2bf(w);
        ushort wl  = f2bf(w - bf2f(wh));
        // negate j-side (KA) => MFMA result = +D
        ushort nhx = phx ^ 0x8000, nhy = phy ^ 0x8000, nhz = phz ^ 0x8000;
        ushort nlx = plx ^ 0x8000, nly = ply ^ 0x8000, nlz = plz ^ 0x8000;
        ushort nwh = wh ^ 0x8000,  nwl = wl ^ 0x8000;
        const ushort one = 0x3F80, none = 0xBF80;
        ushort ka0[8] = {nwh, nwl, none, none, nhx, nhy, nhz, nhx};
        ushort ka1[8] = {nhy, nhz, nlx, nly, nlz, nlx, nly, nlz};
        ushort qb0[8] = {one, one, wh, wl, phx, phy, phz, plx};
        ushort qb1[8] = {ply, plz, phx, phy, phz, plx, ply, plz};
        *(uint4*)&KA[(size_t)i * 8]       = *(uint4*)ka0;
        *(uint4*)&KA[((size_t)N + i) * 8] = *(uint4*)ka1;
        *(uint4*)&QB[(size_t)i * 8]       = *(uint4*)qb0;
        *(uint4*)&QB[((size_t)N + i) * 8] = *(uint4*)qb1;
    }

    // W2e = W2 @ We  (+ b2e) over the first 15 blocks
    if (blockIdx.x < 15) {
        int idx = blockIdx.x * 256 + threadIdx.x;      // 0..3839
        int f = idx / 30, o = idx - f * 30;
        float acc = 0.f;
#pragma unroll
        for (int d = 0; d < D_OUT; ++d)
            acc = fmaf(W2[f * D_OUT + d], We[d * D_OUT + o], acc);
        W2e[idx] = acc;
        if (idx < D_OUT) {
            float a2 = be[idx];
#pragma unroll
            for (int d = 0; d < D_OUT; ++d)
                a2 = fmaf(b2[d], We[d * D_OUT + idx], a2);
            b2e[idx] = a2;
        }
    }

    __syncthreads();
    // VWo^T: row c (0..29) = (V@Wo) col c; row 30 = 0; row 31 = 1.0
    const int io = threadIdx.x >> 5, c = threadIdx.x & 31;
    const int ii = blockIdx.x * 8 + io;
    float val;
    if (c < 30) {
        float acc = 0.f;
#pragma unroll
        for (int hh = 0; hh < HID; ++hh)
            acc = fmaf(bf2f(sv[io][hh]), Wo[hh * D_OUT + c], acc);
        val = acc;
    } else {
        val = (c == 31) ? 1.0f : 0.f;
    }
    VWot[(size_t)c * N + ii] = f2bf(val);
}

// ---------------------------------------------------------------------------
// Per-chunk AABB (128 sorted points per chunk), scaled coords.
// ---------------------------------------------------------------------------
__global__ __launch_bounds__(128) void dv_aabb_kernel(
    const float4* __restrict__ pos_s, float4* __restrict__ aabb)
{
    const int cid = blockIdx.x, t = threadIdx.x;
    float4 p = pos_s[cid * 128 + t];
    float mnx = p.x, mny = p.y, mnz = p.z;
    float mxx = p.x, mxy = p.y, mxz = p.z;
#pragma unroll
    for (int m = 1; m < 64; m <<= 1) {
        mnx = fminf(mnx, __shfl_xor(mnx, m, 64));
        mny = fminf(mny, __shfl_xor(mny, m, 64));
        mnz = fminf(mnz, __shfl_xor(mnz, m, 64));
        mxx = fmaxf(mxx, __shfl_xor(mxx, m, 64));
        mxy = fmaxf(mxy, __shfl_xor(mxy, m, 64));
        mxz = fmaxf(mxz, __shfl_xor(mxz, m, 64));
    }
    __shared__ float4 smn[2], smx[2];
    if ((t & 63) == 0) {
        smn[t >> 6] = make_float4(mnx, mny, mnz, 0.f);
        smx[t >> 6] = make_float4(mxx, mxy, mxz, 0.f);
    }
    __syncthreads();
    if (t == 0) {
        float4 a = smn[0], b = smn[1];
        aabb[cid * 2] = make_float4(fminf(a.x, b.x), fminf(a.y, b.y), fminf(a.z, b.z), 0.f);
        a = smx[0]; b = smx[1];
        aabb[cid * 2 + 1] = make_float4(fmaxf(a.x, b.x), fmaxf(a.y, b.y), fmaxf(a.z, b.z), 0.f);
    }
}

// ---------------------------------------------------------------------------
// Kernel B: fused MFMA attention with AABB chunk skipping + reg prefetch.
// Chunks with scaled min-dist^2 > DCUT2 dropped (decay <= 2^-24, bounded).
// ---------------------------------------------------------------------------
__global__ __launch_bounds__(256, 2) void dv_attn_kernel(
    const ushort* __restrict__ Qb, const ushort* __restrict__ Kb,
    const ushort* __restrict__ VWot, const ushort* __restrict__ KA,
    const ushort* __restrict__ QB, const float4* __restrict__ aabb,
    float* __restrict__ partial)
{
    __shared__ ushort lK[128 * 32];    // K tile, 16B-chunk rot swizzle
    __shared__ ushort lV[32 * 128];    // VWo^T tile, 8B-chunk XOR swizzle
    __shared__ ushort lKA[2][128 * 8]; // gate A-side aug

    const int tid  = threadIdx.x;
    const int lane = tid & 63;
    const int wv   = tid >> 6;
    const int h2   = lane >> 5;
    const int l31  = lane & 31;
    const int rb   = blockIdx.x & 63;
    const int jg   = blockIdx.x >> 6;
    const int i0w  = rb * 128 + wv * 32;

    const ushort* qp = Qb + (size_t)(i0w + l31) * HID + h2 * 8;
    const short8 qf0 = *(const short8*)qp;
    const short8 qf1 = *(const short8*)(qp + 16);
    const short8 qaug = *(const short8*)&QB[((size_t)h2 * N + i0w + l31) * 8];

    f32x16 zacc, oacc;
#pragma unroll
    for (int r = 0; r < 16; ++r) { zacc[r] = 0.f; oacc[r] = 0.f; }

    const int cA0 = (h2 + (l31 >> 1)) & 3;
    const int cA1 = (cA0 + 2) & 3;

    // AABB skip mask for this (i-chunk = rb, jg)'s NCH chunks (block-uniform)
    uint32_t mask = 0;
    {
        float4 amin = aabb[2 * rb], amax = aabb[2 * rb + 1];
#pragma unroll
        for (int c = 0; c < NCH; ++c) {
            int cid = jg * NCH + c;
            float4 bmin = aabb[2 * cid], bmax = aabb[2 * cid + 1];
            float dx = fmaxf(0.f, fmaxf(amin.x - bmax.x, bmin.x - amax.x));
            float dy = fmaxf(0.f, fmaxf(amin.y - bmax.y, bmin.y - amax.y));
            float dz = fmaxf(0.f, fmaxf(amin.z - bmax.z, bmin.z - amax.z));
            float d2 = fmaf(dx, dx, fmaf(dy, dy, dz * dz));
            if (d2 > DCUT2) mask |= (1u << c);
        }
    }

    // staging indices (fixed per thread)
    const int kjr0 = tid >> 2,          kcc0 = tid & 3;
    const int kjr1 = (tid + 256) >> 2,  kcc1 = (tid + 256) & 3;
    const int kc20 = (kcc0 + (kjr0 >> 1)) & 3;
    const int kc21 = (kcc1 + (kjr1 >> 1)) & 3;
    const int vhh[4] = { tid >> 5, (tid + 256) >> 5, (tid + 512) >> 5, (tid + 768) >> 5 };
    const int vcx = tid & 31;
    const int ahalf = tid >> 7, ajj = tid & 127;

    uint4 kreg[2];
    uint2 vreg[4];
    uint4 kareg;

    auto LOADC = [&](int c) {
        const int j0 = (jg * NCH + c) << 7;
        kreg[0] = *(const uint4*)&Kb[(size_t)(j0 + kjr0) * HID + kcc0 * 8];
        kreg[1] = *(const uint4*)&Kb[(size_t)(j0 + kjr1) * HID + kcc1 * 8];
#pragma unroll
        for (int r2 = 0; r2 < 4; ++r2)
            vreg[r2] = *(const uint2*)&VWot[(size_t)vhh[r2] * N + j0 + vcx * 4];
        kareg = *(const uint4*)&KA[((size_t)ahalf * N + j0 + ajj) * 8];
    };

    int cur = -1;
    for (int c = 0; c < NCH; ++c)
        if (!(mask & (1u << c))) { cur = c; break; }
    if (cur >= 0) LOADC(cur);

    while (cur >= 0) {
        int nxt = -1;
        for (int c = cur + 1; c < NCH; ++c)
            if (!(mask & (1u << c))) { nxt = c; break; }

        __syncthreads();   // previous compute done; LDS free
        *(uint4*)&lK[kjr0 * 32 + kc20 * 8] = kreg[0];
        *(uint4*)&lK[kjr1 * 32 + kc21 * 8] = kreg[1];
#pragma unroll
        for (int r2 = 0; r2 < 4; ++r2)
            *(uint2*)&lV[vhh[r2] * 128 + (vcx ^ vhh[r2]) * 4] = vreg[r2];
        *(uint4*)&lKA[ahalf][ajj * 8] = kareg;
        __syncthreads();   // LDS ready

        if (nxt >= 0) LOADC(nxt);   // lands under this chunk's compute

#pragma unroll
        for (int t32 = 0; t32 < 4; ++t32) {
            const ushort* krow = &lK[(t32 * 32 + l31) * 32];
            short8 kf0 = *(const short8*)&krow[cA0 * 8];
            short8 kf1 = *(const short8*)&krow[cA1 * 8];
            f32x16 s = __builtin_amdgcn_mfma_f32_32x32x16_bf16(kf0, qf0, zacc, 0, 0, 0);
            s = __builtin_amdgcn_mfma_f32_32x32x16_bf16(kf1, qf1, s, 0, 0, 0);

            short8 kaug = *(const short8*)&lKA[h2][(t32 * 32 + l31) * 8];
            f32x16 gA = __builtin_amdgcn_mfma_f32_32x32x16_bf16(kaug, qaug, zacc, 0, 0, 0);

            uint32_t pk[8];
#pragma unroll
            for (int p = 0; p < 8; ++p) {
                // a = 2^-D * rcp(1 + 2^-S'); all factors bounded
                float eg0 = __builtin_amdgcn_exp2f(-gA[2 * p]);
                float es0 = __builtin_amdgcn_exp2f(-s[2 * p]);
                float a0  = eg0 * __builtin_amdgcn_rcpf(1.0f + es0);
                float eg1 = __builtin_amdgcn_exp2f(-gA[2 * p + 1]);
                float es1 = __builtin_amdgcn_exp2f(-s[2 * p + 1]);
                float a1  = eg1 * __builtin_amdgcn_rcpf(1.0f + es1);
                asm("v_cvt_pk_bf16_f32 %0, %1, %2" : "=v"(pk[p]) : "v"(a0), "v"(a1));
            }
            union BV { uint32_t u[4]; short8 v; };
            BV fa, fb;
            fa.u[0] = pk[0]; fa.u[1] = pk[1]; fa.u[2] = pk[2]; fa.u[3] = pk[3];
            fb.u[0] = pk[4]; fb.u[1] = pk[5]; fb.u[2] = pk[6]; fb.u[3] = pk[7];

            const ushort* vrow = &lV[l31 * 128];
            const int cb = t32 * 8 + h2;
            BV b0, b1;
            *(uint2*)&b0.u[0] = *(const uint2*)&vrow[((cb    ) ^ l31) * 4];
            *(uint2*)&b0.u[2] = *(const uint2*)&vrow[((cb + 2) ^ l31) * 4];
            *(uint2*)&b1.u[0] = *(const uint2*)&vrow[((cb + 4) ^ l31) * 4];
            *(uint2*)&b1.u[2] = *(const uint2*)&vrow[((cb + 6) ^ l31) * 4];

            oacc = __builtin_amdgcn_mfma_f32_32x32x16_bf16(fa.v, b0.v, oacc, 0, 0, 0);
            oacc = __builtin_amdgcn_mfma_f32_32x32x16_bf16(fb.v, b1.v, oacc, 0, 0, 0);
        }
        cur = nxt;
    }

    // partial[i][jg*32 + c]: c<30 = raw pre-Wo H, c==31 = rowsum
#pragma unroll
    for (int r = 0; r < 16; ++r) {
        int ir = (r & 3) + 8 * (r >> 2) + 4 * h2 + i0w;
        partial[(size_t)ir * (JGC * 32) + jg * 32 + l31] = oacc[r];
    }
}

// ---------------------------------------------------------------------------
// Kernel C: epilogue v4 (wave-per-row, zero barriers) + un-permute output.
// ---------------------------------------------------------------------------
__global__ __launch_bounds__(256) void dv_epilogue_kernel(
    const float* __restrict__ partial, const int* __restrict__ perm,
    const float* __restrict__ bo,
    const float* __restrict__ ln_g, const float* __restrict__ ln_b,
    const float* __restrict__ W1, const float* __restrict__ b1,
    const float* __restrict__ W2e, const float* __restrict__ b2e,
    float* __restrict__ out)
{
    __shared__ float shf[4][FFD];    // per-wave private silu slice

    const int tid  = threadIdx.x;
    const int wv   = tid >> 6;
    const int lane = tid & 63;
    const int row  = blockIdx.x * 4 + wv;
    const int orow = perm[row];
    const int c    = lane & 31;
    const bool a30 = c < 30;
    const int  c30 = a30 ? c : 0;

    // P1: row's 512 partial floats; lane reads 8 (stride 64), fold lane^32.
    float s8 = 0.f;
    {
        const float* pp = partial + (size_t)row * (JGC * 32) + lane;
#pragma unroll
        for (int q = 0; q < 8; ++q) s8 += pp[q * 64];
    }
    float sv = s8 + __shfl_xor(s8, 32, 64);   // col sums, dup in both halves

    float rsum = __shfl(sv, 31, 32);          // col 31 = rowsum
    float inv  = __builtin_amdgcn_rcpf(rsum + 1e-8f);
    float Hl   = a30 ? fmaf(sv, inv, bo[c30]) : 0.f;

    // LayerNorm in-register (width-32; lanes with c>=30 contribute 0)
    float x = Hl;
#pragma unroll
    for (int m = 1; m < 32; m <<= 1) x += __shfl_xor(x, m, 32);
    float mu = x * (1.0f / D_OUT);
    float d  = a30 ? (Hl - mu) : 0.f;
    float v2 = d * d;
#pragma unroll
    for (int m = 1; m < 32; m <<= 1) v2 += __shfl_xor(v2, m, 32);
    float rs = rsqrtf(v2 * (1.0f / D_OUT) + 1e-5f);
    float Hn = fmaf(d * rs, ln_g[c30], ln_b[c30]);  // valid where a30

    // FFN1 + SiLU: lane owns f = lane and f = lane + 64 (coalesced W1 rows)
    float acc0 = b1[lane], acc1 = b1[lane + 64];
#pragma unroll
    for (int o = 0; o < D_OUT; ++o) {
        float ho = rdlane(Hn, o);             // lane o < 30 holds Hn[o]
        acc0 = fmaf(ho, W1[o * FFD + lane], acc0);
        acc1 = fmaf(ho, W1[o * FFD + lane + 64], acc1);
    }
    const float L2E = 1.4426950408889634f;
    shf[wv][lane] =
        acc0 * __builtin_amdgcn_rcpf(1.0f + __builtin_amdgcn_exp2f(-acc0 * L2E));
    shf[wv][lane + 64] =
        acc1 * __builtin_amdgcn_rcpf(1.0f + __builtin_amdgcn_exp2f(-acc1 * L2E));
    // same-wave ds_write -> ds_read: ordered by lgkmcnt, no barrier needed

    // FFN2e: half-wave h covers f in [h*64, h*64+64); o = c30 per lane.
    const int half = lane >> 5;
    float acc = 0.f;
    {
        const float* hbase = &shf[wv][half * 64];
#pragma unroll
        for (int k = 0; k < 16; ++k) {
            float4 hv = *(const float4*)&hbase[k * 4];
            const int f0 = half * 64 + k * 4;
            acc = fmaf(hv.x, W2e[(f0    ) * D_OUT + c30], acc);
            acc = fmaf(hv.y, W2e[(f0 + 1) * D_OUT + c30], acc);
            acc = fmaf(hv.z, W2e[(f0 + 2) * D_OUT + c30], acc);
            acc = fmaf(hv.w, W2e[(f0 + 3) * D_OUT + c30], acc);
        }
    }
    float val = acc + __shfl_xor(acc, 32, 64) + b2e[c30];

    if (lane < 32 && a30)
        out[(size_t)orow * ZC + c] = val;

    float kep = a30 ? val * val : 0.f;
#pragma unroll
    for (int m = 1; m < 32; m <<= 1) kep += __shfl_xor(kep, m, 32);
    if (lane == 0) {
        float* op = out + (size_t)orow * ZC;
        op[30] = 0.f; op[31] = 0.f; op[32] = 0.f;
        op[33] = kep * (0.5f / D_OUT);
    }
}

// ---------------------------------------------------------------------------
extern "C" void kernel_launch(void* const* d_in, const int* in_sizes, int n_in,
                              void* d_out, int out_size, void* d_ws, size_t ws_size,
                              hipStream_t stream)
{
    const float* Z  = (const float*)d_in[1];
    const float* Wq = (const float*)d_in[2];
    const float* bq = (const float*)d_in[3];
    const float* Wk = (const float*)d_in[4];
    const float* bk = (const float*)d_in[5];
    const float* Wv = (const float*)d_in[6];
    const float* bv = (const float*)d_in[7];
    const float* Wo = (const float*)d_in[8];
    const float* bo = (const float*)d_in[9];
    const float* lg = (const float*)d_in[10];
    const float* lb = (const float*)d_in[11];
    const float* W1 = (const float*)d_in[12];
    const float* b1 = (const float*)d_in[13];
    const float* W2 = (const float*)d_in[14];
    const float* b2 = (const float*)d_in[15];
    const float* We = (const float*)d_in[16];
    const float* be = (const float*)d_in[17];
    float* out = (float*)d_out;

    ushort* Qb   = (ushort*)d_ws;                 // N*32 bf16
    ushort* Kb   = Qb + (size_t)N * HID;          // N*32 bf16
    ushort* VWot = Kb + (size_t)N * HID;          // [32][N] bf16 (V@Wo)^T
    ushort* KA   = VWot + (size_t)N * HID;        // [2][N][8] bf16
    ushort* QB   = KA + (size_t)N * 16;           // [2][N][8] bf16
    float*  W2e  = (float*)(QB + (size_t)N * 16); // [128][30]
    float*  b2e  = W2e + FFD * D_OUT;             // [30] (+pad to 32)
    float4* pos_s = (float4*)(b2e + 32);          // [N]
    float4* aabb  = pos_s + N;                    // [64][2]
    int*    key   = (int*)(aabb + 2 * NCHUNK);    // [N]
    int*    perm  = key + N;                      // [N]
    int*    hist  = perm + N;                     // [4096]
    int*    offs  = hist + 4096;                  // [4096]
    float*  partial = (float*)(offs + 4096);      // [N][JGC*32] f32

    hipMemsetAsync(hist, 0, 4096 * sizeof(int), stream);
    hipLaunchKernelGGL(dv_hist_kernel, dim3(N / 256), dim3(256), 0, stream,
                       Z, key, hist);
    hipLaunchKernelGGL(dv_scan_kernel, dim3(1), dim3(256), 0, stream,
                       hist, offs);
    hipLaunchKernelGGL(dv_scatter_kernel, dim3(N / 256), dim3(256), 0, stream,
                       key, offs, perm);
    hipLaunchKernelGGL(dv_qkv_kernel, dim3((N * HID) / 256), dim3(256), 0, stream,
                       Z, perm, Wq, bq, Wk, bk, Wv, bv, Wo, W2, We, b2, be,
                       Qb, Kb, VWot, KA, QB, pos_s, W2e, b2e);
    hipLaunchKernelGGL(dv_aabb_kernel, dim3(NCHUNK), dim3(128), 0, stream,
                       pos_s, aabb);
    hipLaunchKernelGGL(dv_attn_kernel, dim3(64 * JGC), dim3(256), 0, stream,
                       Qb, Kb, VWot, KA, QB, aabb, partial);
    hipLaunchKernelGGL(dv_epilogue_kernel, dim3(N / 4), dim3(256), 0, stream,
                       partial, perm, bo, lg, lb, W1, b1, W2e, b2e, out);
}

// Round 16
// 59.321 us; speedup vs baseline: 1.2755x; 1.2755x over previous
//
#include <hip/hip_runtime.h>
#include <hip/hip_bf16.h>

#define N      8192
#define D_IN   30
#define HID    32
#define D_OUT  30
#define FFD    128
#define ZC     34
#define JGC    16     // j-split groups

typedef __attribute__((ext_vector_type(8))) short short8;
typedef __attribute__((ext_vector_type(16))) float f32x16;

static __device__ __forceinline__ ushort f2bf(float x) {
    uint32_t u = __float_as_uint(x);
    uint32_t r = (u + 0x7fffu + ((u >> 16) & 1u)) >> 16;   // RTNE
    return (ushort)r;
}
static __device__ __forceinline__ float bf2f(ushort u) {
    return __uint_as_float(((uint32_t)u) << 16);
}
static __device__ __forceinline__ float rdlane(float v, int l) {
    return __uint_as_float(__builtin_amdgcn_readlane(__float_as_uint(v), l));
}

// ---------------------------------------------------------------------------
// Kernel A (R10/R14-identical): QKV -> bf16; VWo^T (row30=0,row31=1 -> PV
// col31 = rowsum); negated split-bf16 gate tables (gate MFMA = +D);
// W2e = W2@We, b2e = b2@We + be.
// ---------------------------------------------------------------------------
__global__ __launch_bounds__(256) void dv_qkv_kernel(
    const float* __restrict__ Z,
    const float* __restrict__ Wq, const float* __restrict__ bq,
    const float* __restrict__ Wk, const float* __restrict__ bk,
    const float* __restrict__ Wv, const float* __restrict__ bv,
    const float* __restrict__ Wo,
    const float* __restrict__ W2, const float* __restrict__ We,
    const float* __restrict__ b2, const float* __restrict__ be,
    ushort* __restrict__ Qb, ushort* __restrict__ Kb,
    ushort* __restrict__ VWot, ushort* __restrict__ KA,
    ushort* __restrict__ QB, float* __restrict__ W2e, float* __restrict__ b2e)
{
    __shared__ ushort sv[8][33];
    const int t = blockIdx.x * 256 + threadIdx.x;
    const int i = t >> 5;
    const int h = t & 31;
    const float* z = Z + (size_t)i * ZC;

    float q = bq[h], k = bk[h], v = bv[h];
#pragma unroll
    for (int d = 0; d < D_IN; ++d) {
        float zf = z[d];
        q = fmaf(zf, Wq[d * HID + h], q);
        k = fmaf(zf, Wk[d * HID + h], k);
        v = fmaf(zf, Wv[d * HID + h], v);
    }
    const float QS = 0.17677669529663687f * 1.4426950408889634f; // log2e/sqrt(32)
    Qb[(size_t)i * HID + h] = f2bf(q * QS);
    Kb[(size_t)i * HID + h] = f2bf(k);
    sv[threadIdx.x >> 5][h] = f2bf(v);

    if (h == 0) {
        float p0 = z[D_IN], p1 = z[D_IN + 1], p2 = z[D_IN + 2];
        const float C2 = 1.4426950408889634f / 0.18f;   // log2e/(2*sigma^2)
        const float SC = sqrtf(2.0f * C2);
        float px = p0 * SC, py = p1 * SC, pz = p2 * SC;
        float w  = -C2 * (p0 * p0 + p1 * p1 + p2 * p2);
        ushort phx = f2bf(px), phy = f2bf(py), phz = f2bf(pz);
        ushort plx = f2bf(px - bf2f(phx));
        ushort ply = f2bf(py - bf2f(phy));
        ushort plz = f2bf(pz - bf2f(phz));
        ushort wh  = f2bf(w);
        ushort wl  = f2bf(w - bf2f(wh));
        // negate j-side (KA) => MFMA result = +D
        ushort nhx = phx ^ 0x8000, nhy = phy ^ 0x8000, nhz = phz ^ 0x8000;
        ushort nlx = plx ^ 0x8000, nly = ply ^ 0x8000, nlz = plz ^ 0x8000;
        ushort nwh = wh ^ 0x8000,  nwl = wl ^ 0x8000;
        const ushort one = 0x3F80, none = 0xBF80;
        ushort ka0[8] = {nwh, nwl, none, none, nhx, nhy, nhz, nhx};
        ushort ka1[8] = {nhy, nhz, nlx, nly, nlz, nlx, nly, nlz};
        ushort qb0[8] = {one, one, wh, wl, phx, phy, phz, plx};
        ushort qb1[8] = {ply, plz, phx, phy, phz, plx, ply, plz};
        *(uint4*)&KA[(size_t)i * 8]       = *(uint4*)ka0;
        *(uint4*)&KA[((size_t)N + i) * 8] = *(uint4*)ka1;
        *(uint4*)&QB[(size_t)i * 8]       = *(uint4*)qb0;
        *(uint4*)&QB[((size_t)N + i) * 8] = *(uint4*)qb1;
    }

    // W2e = W2 @ We  (+ b2e) over the first 15 blocks
    if (blockIdx.x < 15) {
        int idx = blockIdx.x * 256 + threadIdx.x;      // 0..3839
        int f = idx / 30, o = idx - f * 30;
        float acc = 0.f;
#pragma unroll
        for (int d = 0; d < D_OUT; ++d)
            acc = fmaf(W2[f * D_OUT + d], We[d * D_OUT + o], acc);
        W2e[idx] = acc;
        if (idx < D_OUT) {
            float a2 = be[idx];
#pragma unroll
            for (int d = 0; d < D_OUT; ++d)
                a2 = fmaf(b2[d], We[d * D_OUT + idx], a2);
            b2e[idx] = a2;
        }
    }

    __syncthreads();
    // VWo^T: row c (0..29) = (V@Wo) col c; row 30 = 0; row 31 = 1.0
    const int io = threadIdx.x >> 5, c = threadIdx.x & 31;
    const int ii = blockIdx.x * 8 + io;
    float val;
    if (c < 30) {
        float acc = 0.f;
#pragma unroll
        for (int hh = 0; hh < HID; ++hh)
            acc = fmaf(bf2f(sv[io][hh]), Wo[hh * D_OUT + c], acc);
        val = acc;
    } else {
        val = (c == 31) ? 1.0f : 0.f;
    }
    VWot[(size_t)c * N + ii] = f2bf(val);
}

// ---------------------------------------------------------------------------
// Kernel B: R14 attention (reg prefetch, bounded gate) with paired-rcp gate:
// r = rcp((1+es0)(1+es1)); a0 = eg0*(1+es1)*r; a1 = eg1*(1+es0)*r.
// Exact algebra, halves rcp count; products <= ~196, fp32-safe.
// ---------------------------------------------------------------------------
__global__ __launch_bounds__(256, 4) void dv_attn_kernel(
    const ushort* __restrict__ Qb, const ushort* __restrict__ Kb,
    const ushort* __restrict__ VWot, const ushort* __restrict__ KA,
    const ushort* __restrict__ QB, float* __restrict__ partial, int nch)
{
    __shared__ ushort lK[128 * 32];    // K tile, 16B-chunk rot swizzle
    __shared__ ushort lV[32 * 128];    // VWo^T tile, 8B-chunk XOR swizzle
    __shared__ ushort lKA[2][128 * 8]; // gate A-side aug

    const int tid  = threadIdx.x;
    const int lane = tid & 63;
    const int wv   = tid >> 6;
    const int h2   = lane >> 5;
    const int l31  = lane & 31;
    const int rb   = blockIdx.x & 63;
    const int jg   = blockIdx.x >> 6;
    const int i0w  = rb * 128 + wv * 32;

    const ushort* qp = Qb + (size_t)(i0w + l31) * HID + h2 * 8;
    const short8 qf0 = *(const short8*)qp;
    const short8 qf1 = *(const short8*)(qp + 16);
    const short8 qaug = *(const short8*)&QB[((size_t)h2 * N + i0w + l31) * 8];

    f32x16 zacc, oacc;
#pragma unroll
    for (int r = 0; r < 16; ++r) { zacc[r] = 0.f; oacc[r] = 0.f; }

    const int cA0 = (h2 + (l31 >> 1)) & 3;
    const int cA1 = (cA0 + 2) & 3;

    // staging indices (fixed per thread)
    const int kjr0 = tid >> 2,          kcc0 = tid & 3;
    const int kjr1 = (tid + 256) >> 2,  kcc1 = (tid + 256) & 3;
    const int kc20 = (kcc0 + (kjr0 >> 1)) & 3;
    const int kc21 = (kcc1 + (kjr1 >> 1)) & 3;
    const int vhh[4] = { tid >> 5, (tid + 256) >> 5, (tid + 512) >> 5, (tid + 768) >> 5 };
    const int vcx = tid & 31;
    const int ahalf = tid >> 7, ajj = tid & 127;

    uint4 kreg[2];
    uint2 vreg[4];
    uint4 kareg;

    // prologue: load chunk 0
    {
        const int j0 = (jg * nch) << 7;
        kreg[0] = *(const uint4*)&Kb[(size_t)(j0 + kjr0) * HID + kcc0 * 8];
        kreg[1] = *(const uint4*)&Kb[(size_t)(j0 + kjr1) * HID + kcc1 * 8];
#pragma unroll
        for (int r2 = 0; r2 < 4; ++r2)
            vreg[r2] = *(const uint2*)&VWot[(size_t)vhh[r2] * N + j0 + vcx * 4];
        kareg = *(const uint4*)&KA[((size_t)ahalf * N + j0 + ajj) * 8];
    }

    for (int ch = 0; ch < nch; ++ch) {
        __syncthreads();   // previous compute done; LDS free
        *(uint4*)&lK[kjr0 * 32 + kc20 * 8] = kreg[0];
        *(uint4*)&lK[kjr1 * 32 + kc21 * 8] = kreg[1];
#pragma unroll
        for (int r2 = 0; r2 < 4; ++r2)
            *(uint2*)&lV[vhh[r2] * 128 + (vcx ^ vhh[r2]) * 4] = vreg[r2];
        *(uint4*)&lKA[ahalf][ajj * 8] = kareg;
        __syncthreads();   // LDS ready

        // issue next chunk's global loads (land under this chunk's compute)
        if (ch + 1 < nch) {
            const int j1 = (jg * nch + ch + 1) << 7;
            kreg[0] = *(const uint4*)&Kb[(size_t)(j1 + kjr0) * HID + kcc0 * 8];
            kreg[1] = *(const uint4*)&Kb[(size_t)(j1 + kjr1) * HID + kcc1 * 8];
#pragma unroll
            for (int r2 = 0; r2 < 4; ++r2)
                vreg[r2] = *(const uint2*)&VWot[(size_t)vhh[r2] * N + j1 + vcx * 4];
            kareg = *(const uint4*)&KA[((size_t)ahalf * N + j1 + ajj) * 8];
        }

#pragma unroll
        for (int t32 = 0; t32 < 4; ++t32) {
            const ushort* krow = &lK[(t32 * 32 + l31) * 32];
            short8 kf0 = *(const short8*)&krow[cA0 * 8];
            short8 kf1 = *(const short8*)&krow[cA1 * 8];
            f32x16 s = __builtin_amdgcn_mfma_f32_32x32x16_bf16(kf0, qf0, zacc, 0, 0, 0);
            s = __builtin_amdgcn_mfma_f32_32x32x16_bf16(kf1, qf1, s, 0, 0, 0);

            short8 kaug = *(const short8*)&lKA[h2][(t32 * 32 + l31) * 8];
            f32x16 gA = __builtin_amdgcn_mfma_f32_32x32x16_bf16(kaug, qaug, zacc, 0, 0, 0);

            uint32_t pk[8];
#pragma unroll
            for (int p = 0; p < 8; ++p) {
                // paired gate: u0 = 1+2^-S'0, u1 = 1+2^-S'1,
                // r = rcp(u0*u1); a0 = 2^-D0 * u1 * r; a1 = 2^-D1 * u0 * r
                float eg0 = __builtin_amdgcn_exp2f(-gA[2 * p]);
                float eg1 = __builtin_amdgcn_exp2f(-gA[2 * p + 1]);
                float u0  = 1.0f + __builtin_amdgcn_exp2f(-s[2 * p]);
                float u1  = 1.0f + __builtin_amdgcn_exp2f(-s[2 * p + 1]);
                float rr  = __builtin_amdgcn_rcpf(u0 * u1);
                float a0  = eg0 * u1 * rr;
                float a1  = eg1 * u0 * rr;
                asm("v_cvt_pk_bf16_f32 %0, %1, %2" : "=v"(pk[p]) : "v"(a0), "v"(a1));
            }
            union BV { uint32_t u[4]; short8 v; };
            BV fa, fb;
            fa.u[0] = pk[0]; fa.u[1] = pk[1]; fa.u[2] = pk[2]; fa.u[3] = pk[3];
            fb.u[0] = pk[4]; fb.u[1] = pk[5]; fb.u[2] = pk[6]; fb.u[3] = pk[7];

            const ushort* vrow = &lV[l31 * 128];
            const int cb = t32 * 8 + h2;
            BV b0, b1;
            *(uint2*)&b0.u[0] = *(const uint2*)&vrow[((cb    ) ^ l31) * 4];
            *(uint2*)&b0.u[2] = *(const uint2*)&vrow[((cb + 2) ^ l31) * 4];
            *(uint2*)&b1.u[0] = *(const uint2*)&vrow[((cb + 4) ^ l31) * 4];
            *(uint2*)&b1.u[2] = *(const uint2*)&vrow[((cb + 6) ^ l31) * 4];

            oacc = __builtin_amdgcn_mfma_f32_32x32x16_bf16(fa.v, b0.v, oacc, 0, 0, 0);
            oacc = __builtin_amdgcn_mfma_f32_32x32x16_bf16(fb.v, b1.v, oacc, 0, 0, 0);
        }
    }

    // partial[i][jg*32 + c]: c<30 = raw pre-Wo H, c==31 = rowsum
#pragma unroll
    for (int r = 0; r < 16; ++r) {
        int ir = (r & 3) + 8 * (r >> 2) + 4 * h2 + i0w;
        partial[(size_t)ir * (JGC * 32) + jg * 32 + l31] = oacc[r];
    }
}

// ---------------------------------------------------------------------------
// Kernel C (R14-identical): epilogue v4 — wave-per-row, zero __syncthreads.
// ---------------------------------------------------------------------------
__global__ __launch_bounds__(256) void dv_epilogue_kernel(
    const float* __restrict__ partial,
    const float* __restrict__ bo,
    const float* __restrict__ ln_g, const float* __restrict__ ln_b,
    const float* __restrict__ W1, const float* __restrict__ b1,
    const float* __restrict__ W2e, const float* __restrict__ b2e,
    float* __restrict__ out)
{
    __shared__ float shf[4][FFD];    // per-wave private silu slice

    const int tid  = threadIdx.x;
    const int wv   = tid >> 6;
    const int lane = tid & 63;
    const int row  = blockIdx.x * 4 + wv;
    const int c    = lane & 31;
    const bool a30 = c < 30;
    const int  c30 = a30 ? c : 0;

    // P1: row's 512 partial floats; lane reads 8 (stride 64), fold lane^32.
    float s8 = 0.f;
    {
        const float* pp = partial + (size_t)row * (JGC * 32) + lane;
#pragma unroll
        for (int q = 0; q < 8; ++q) s8 += pp[q * 64];
    }
    float sv = s8 + __shfl_xor(s8, 32, 64);   // col sums, dup in both halves

    float rsum = __shfl(sv, 31, 32);          // col 31 = rowsum
    float inv  = __builtin_amdgcn_rcpf(rsum + 1e-8f);
    float Hl   = a30 ? fmaf(sv, inv, bo[c30]) : 0.f;

    // LayerNorm in-register (width-32; lanes with c>=30 contribute 0)
    float x = Hl;
#pragma unroll
    for (int m = 1; m < 32; m <<= 1) x += __shfl_xor(x, m, 32);
    float mu = x * (1.0f / D_OUT);
    float d  = a30 ? (Hl - mu) : 0.f;
    float v2 = d * d;
#pragma unroll
    for (int m = 1; m < 32; m <<= 1) v2 += __shfl_xor(v2, m, 32);
    float rs = rsqrtf(v2 * (1.0f / D_OUT) + 1e-5f);
    float Hn = fmaf(d * rs, ln_g[c30], ln_b[c30]);  // valid where a30

    // FFN1 + SiLU: lane owns f = lane and f = lane + 64 (coalesced W1 rows)
    float acc0 = b1[lane], acc1 = b1[lane + 64];
#pragma unroll
    for (int o = 0; o < D_OUT; ++o) {
        float ho = rdlane(Hn, o);             // lane o < 30 holds Hn[o]
        acc0 = fmaf(ho, W1[o * FFD + lane], acc0);
        acc1 = fmaf(ho, W1[o * FFD + lane + 64], acc1);
    }
    const float L2E = 1.4426950408889634f;
    shf[wv][lane] =
        acc0 * __builtin_amdgcn_rcpf(1.0f + __builtin_amdgcn_exp2f(-acc0 * L2E));
    shf[wv][lane + 64] =
        acc1 * __builtin_amdgcn_rcpf(1.0f + __builtin_amdgcn_exp2f(-acc1 * L2E));
    // same-wave ds_write -> ds_read: ordered by lgkmcnt, no barrier needed

    // FFN2e: half-wave h covers f in [h*64, h*64+64); o = c30 per lane.
    const int half = lane >> 5;
    float acc = 0.f;
    {
        const float* hbase = &shf[wv][half * 64];
#pragma unroll
        for (int k = 0; k < 16; ++k) {
            float4 hv = *(const float4*)&hbase[k * 4];
            const int f0 = half * 64 + k * 4;
            acc = fmaf(hv.x, W2e[(f0    ) * D_OUT + c30], acc);
            acc = fmaf(hv.y, W2e[(f0 + 1) * D_OUT + c30], acc);
            acc = fmaf(hv.z, W2e[(f0 + 2) * D_OUT + c30], acc);
            acc = fmaf(hv.w, W2e[(f0 + 3) * D_OUT + c30], acc);
        }
    }
    float val = acc + __shfl_xor(acc, 32, 64) + b2e[c30];

    if (lane < 32 && a30)
        out[(size_t)row * ZC + c] = val;

    float kep = a30 ? val * val : 0.f;
#pragma unroll
    for (int m = 1; m < 32; m <<= 1) kep += __shfl_xor(kep, m, 32);
    if (lane == 0) {
        float* op = out + (size_t)row * ZC;
        op[30] = 0.f; op[31] = 0.f; op[32] = 0.f;
        op[33] = kep * (0.5f / D_OUT);
    }
}

// ---------------------------------------------------------------------------
extern "C" void kernel_launch(void* const* d_in, const int* in_sizes, int n_in,
                              void* d_out, int out_size, void* d_ws, size_t ws_size,
                              hipStream_t stream)
{
    const float* Z  = (const float*)d_in[1];
    const float* Wq = (const float*)d_in[2];
    const float* bq = (const float*)d_in[3];
    const float* Wk = (const float*)d_in[4];
    const float* bk = (const float*)d_in[5];
    const float* Wv = (const float*)d_in[6];
    const float* bv = (const float*)d_in[7];
    const float* Wo = (const float*)d_in[8];
    const float* bo = (const float*)d_in[9];
    const float* lg = (const float*)d_in[10];
    const float* lb = (const float*)d_in[11];
    const float* W1 = (const float*)d_in[12];
    const float* b1 = (const float*)d_in[13];
    const float* W2 = (const float*)d_in[14];
    const float* b2 = (const float*)d_in[15];
    const float* We = (const float*)d_in[16];
    const float* be = (const float*)d_in[17];
    float* out = (float*)d_out;

    ushort* Qb   = (ushort*)d_ws;                 // N*32 bf16
    ushort* Kb   = Qb + (size_t)N * HID;          // N*32 bf16
    ushort* VWot = Kb + (size_t)N * HID;          // [32][N] bf16 (V@Wo)^T
    ushort* KA   = VWot + (size_t)N * HID;        // [2][N][8] bf16
    ushort* QB   = KA + (size_t)N * 16;           // [2][N][8] bf16
    float*  W2e  = (float*)(QB + (size_t)N * 16); // [128][30]
    float*  b2e  = W2e + FFD * D_OUT;             // [30] (+pad)
    float*  partial = b2e + 32;                   // [N][JGC*32] f32

    int nch = N / (JGC * 128);

    hipLaunchKernelGGL(dv_qkv_kernel, dim3((N * HID) / 256), dim3(256), 0, stream,
                       Z, Wq, bq, Wk, bk, Wv, bv, Wo, W2, We, b2, be,
                       Qb, Kb, VWot, KA, QB, W2e, b2e);
    hipLaunchKernelGGL(dv_attn_kernel, dim3(64 * JGC), dim3(256), 0, stream,
                       Qb, Kb, VWot, KA, QB, partial, nch);
    hipLaunchKernelGGL(dv_epilogue_kernel, dim3(N / 4), dim3(256), 0, stream,
                       partial, bo, lg, lb, W1, b1, W2e, b2e, out);
}